// Round 6
// baseline (213.617 us; speedup 1.0000x reference)
//
#include <hip/hip_runtime.h>
#include <math.h>

#define MROWS 8192   // T*B flat rows
#define DM    512    // d_model
#define SEQL  2048   // attention sequence (rows per batch group)
#define HDIM  64
#define NSPLIT 2     // key-dimension split for attention occupancy

typedef __attribute__((ext_vector_type(4))) float floatx4;
typedef _Float16 half2v __attribute__((ext_vector_type(2)));
typedef _Float16 half4v __attribute__((ext_vector_type(4)));
typedef _Float16 half8v __attribute__((ext_vector_type(8)));

#define CEXP 0.18033688011f   // log2(e)/8 — folded into Wq/bq at prep time

// async global->LDS, 16B per lane; LDS dst must be uniform_base + lane*16
__device__ __forceinline__ void gll16(const void* g, void* l) {
    __builtin_amdgcn_global_load_lds(
        (const __attribute__((address_space(1))) unsigned int*)g,
        (__attribute__((address_space(3))) unsigned int*)l, 16, 0, 0);
}

__device__ __forceinline__ half4v pack4(float a, float b, float c, float d) {
    half2v lo = __builtin_bit_cast(half2v, __builtin_amdgcn_cvt_pkrtz(a, b));
    half2v hi = __builtin_bit_cast(half2v, __builtin_amdgcn_cvt_pkrtz(c, d));
    half4v r;
    r[0] = lo[0]; r[1] = lo[1]; r[2] = hi[0]; r[3] = hi[1];
    return r;
}

// ---------------------------------------------------------------------------
// cast three (T,B,C) f32 inputs to f16
// ---------------------------------------------------------------------------
__global__ __launch_bounds__(256) void cast3(const float* __restrict__ s0,
                                             const float* __restrict__ s1,
                                             const float* __restrict__ s2,
                                             _Float16* __restrict__ d0,
                                             _Float16* __restrict__ d1,
                                             _Float16* __restrict__ d2) {
    const float* s = blockIdx.z == 0 ? s0 : (blockIdx.z == 1 ? s1 : s2);
    _Float16* d = blockIdx.z == 0 ? d0 : (blockIdx.z == 1 ? d1 : d2);
    const size_t i = ((size_t)blockIdx.x * 256 + threadIdx.x) * 8;
    const float4 f0 = *(const float4*)&s[i];
    const float4 f1 = *(const float4*)&s[i + 4];
    half8v o;
    o[0] = (_Float16)f0.x; o[1] = (_Float16)f0.y; o[2] = (_Float16)f0.z; o[3] = (_Float16)f0.w;
    o[4] = (_Float16)f1.x; o[5] = (_Float16)f1.y; o[6] = (_Float16)f1.z; o[7] = (_Float16)f1.w;
    *(half8v*)&d[i] = o;
}

// ---------------------------------------------------------------------------
// transpose+cast 512x512 f32 weights -> f16 [N][K]; Wq (z==0) pre-scaled by CEXP
// ---------------------------------------------------------------------------
__global__ __launch_bounds__(256) void transw(const float* __restrict__ w0,
                                              const float* __restrict__ w1,
                                              const float* __restrict__ w2,
                                              const float* __restrict__ w3,
                                              _Float16* __restrict__ t0,
                                              _Float16* __restrict__ t1,
                                              _Float16* __restrict__ t2,
                                              _Float16* __restrict__ t3) {
    __shared__ float tile[32][33];
    const float* W = blockIdx.z == 0 ? w0 : (blockIdx.z == 1 ? w1 : (blockIdx.z == 2 ? w2 : w3));
    _Float16* T = blockIdx.z == 0 ? t0 : (blockIdx.z == 1 ? t1 : (blockIdx.z == 2 ? t2 : t3));
    const float sc = (blockIdx.z == 0) ? CEXP : 1.0f;
    const int tx = threadIdx.x & 31, ty = threadIdx.x >> 5;  // 32 x 8
    const int x = blockIdx.x * 32 + tx;
    const int y0 = blockIdx.y * 32;
#pragma unroll
    for (int i = 0; i < 4; ++i)
        tile[ty + i * 8][tx] = W[(size_t)(y0 + ty + i * 8) * DM + x];
    __syncthreads();
    const int xo = y0 + tx;
#pragma unroll
    for (int i = 0; i < 4; ++i)
        T[(size_t)(blockIdx.x * 32 + ty + i * 8) * DM + xo] = (_Float16)(tile[tx][ty + i * 8] * sc);
}

// ---------------------------------------------------------------------------
// GEMM: out[M x 512] = A[M x 512] * Bt^T + bias*bscale  (A, Bt f16 [.][K])
// 128x64 tile, BK=64, 4 waves each 32 rows x 64 cols, MFMA 16x16x32 f16,
// xor-swizzled LDS.  grid (N/64, M/128, z).  mode per z: 0 = f16 row-major,
// 1 = f16 Vt-layout, 2 = f32 row-major.
// ---------------------------------------------------------------------------
__global__ __launch_bounds__(256, 3) void gemm_f16(
        const _Float16* __restrict__ A0, const _Float16* __restrict__ A1, const _Float16* __restrict__ A2,
        const _Float16* __restrict__ B0, const _Float16* __restrict__ B1, const _Float16* __restrict__ B2,
        const float* __restrict__ c0, const float* __restrict__ c1, const float* __restrict__ c2,
        void* __restrict__ o0, void* __restrict__ o1, void* __restrict__ o2,
        int modes, float bscale0) {
    __shared__ _Float16 As[128 * 64];   // 16 KB
    __shared__ _Float16 Bs[64 * 64];    //  8 KB
    const int z = blockIdx.z;
    const _Float16* A  = z == 0 ? A0 : (z == 1 ? A1 : A2);
    const _Float16* Bt = z == 0 ? B0 : (z == 1 ? B1 : B2);
    const float* bias  = z == 0 ? c0 : (z == 1 ? c1 : c2);
    void* outp         = z == 0 ? o0 : (z == 1 ? o1 : o2);
    const int mode = (modes >> (z * 4)) & 15;
    const float bscale = (z == 0) ? bscale0 : 1.0f;

    const int tid = threadIdx.x;
    const int w = tid >> 6;
    const int l15 = tid & 15, quad = (tid & 63) >> 4;
    const int n0 = blockIdx.x * 64, m0 = blockIdx.y * 128;

    floatx4 acc[2][4];
#pragma unroll
    for (int i = 0; i < 2; ++i)
#pragma unroll
        for (int j = 0; j < 4; ++j) acc[i][j] = (floatx4){0.f, 0.f, 0.f, 0.f};

    for (int kt = 0; kt < DM / 64; ++kt) {
        __syncthreads();
#pragma unroll
        for (int i = 0; i < 4; ++i) {          // A: 1024 chunks
            const int c = i * 256 + tid;
            const int row = c >> 3, g = c & 7;
            const int kg = g ^ (row & 7);
            gll16(&A[(size_t)(m0 + row) * DM + kt * 64 + kg * 8], &As[c * 8]);
        }
#pragma unroll
        for (int i = 0; i < 2; ++i) {          // B: 512 chunks
            const int c = i * 256 + tid;
            const int row = c >> 3, g = c & 7;
            const int kg = g ^ (row & 7);
            gll16(&Bt[(size_t)(n0 + row) * DM + kt * 64 + kg * 8], &Bs[c * 8]);
        }
        __syncthreads();
#pragma unroll
        for (int ks = 0; ks < 2; ++ks) {
            half8v af[2], bfr[4];
#pragma unroll
            for (int i = 0; i < 2; ++i) {
                const int row = w * 32 + i * 16 + l15;
                af[i] = *(const half8v*)&As[row * 64 + ((ks * 4 + quad) ^ (row & 7)) * 8];
            }
#pragma unroll
            for (int j = 0; j < 4; ++j) {
                const int row = j * 16 + l15;
                bfr[j] = *(const half8v*)&Bs[row * 64 + ((ks * 4 + quad) ^ (row & 7)) * 8];
            }
#pragma unroll
            for (int i = 0; i < 2; ++i)
#pragma unroll
                for (int j = 0; j < 4; ++j)
                    acc[i][j] = __builtin_amdgcn_mfma_f32_16x16x32_f16(af[i], bfr[j], acc[i][j], 0, 0, 0);
        }
    }
    // epilogue: C/D layout col=lane&15, row=quad*4+reg
#pragma unroll
    for (int j = 0; j < 4; ++j) {
        const int col = n0 + j * 16 + l15;
        const float bv = bias[col] * bscale;
#pragma unroll
        for (int i = 0; i < 2; ++i) {
            const int rb = m0 + w * 32 + i * 16 + quad * 4;
            if (mode == 2) {
                float* of = (float*)outp;
#pragma unroll
                for (int r = 0; r < 4; ++r)
                    of[(size_t)(rb + r) * DM + col] = acc[i][j][r] + bv;
            } else if (mode == 0) {
                _Float16* oh = (_Float16*)outp;
#pragma unroll
                for (int r = 0; r < 4; ++r)
                    oh[(size_t)(rb + r) * DM + col] = (_Float16)(acc[i][j][r] + bv);
            } else {  // mode 1: Vt[g][col][seq], 4 consecutive seq -> one 8B store
                _Float16* oh = (_Float16*)outp;
                const int g = rb >> 11, seq = rb & 2047;
                half4v pv;
#pragma unroll
                for (int r = 0; r < 4; ++r) pv[r] = (_Float16)(acc[i][j][r] + bv);
                *(half4v*)&oh[((size_t)g * DM + col) * SEQL + seq] = pv;
            }
        }
    }
}

// ---------------------------------------------------------------------------
// Flash attention, f16 MFMA, S^T orientation, fixed-scale softmax, split-K.
// grid (16 q-tiles, 32 (g,h) pairs, NSPLIT key-splits); 256 threads.
// Each split covers SEQL/NSPLIT keys; writes unnormalized O (f16) + l (f32).
// Fixed-scale softmax => partials combine as (O1+O2)/(l1+l2), no max state.
// ---------------------------------------------------------------------------
__global__ __launch_bounds__(256, 4) void attn_mfma(const _Float16* __restrict__ Q16,
                                                    const _Float16* __restrict__ K16,
                                                    const _Float16* __restrict__ Vt,
                                                    _Float16* __restrict__ Opart,
                                                    float* __restrict__ lpart) {
    __shared__ _Float16 Ks[2][64 * 64];   // [key][d], xor-swizzled d-groups
    __shared__ _Float16 Vs[2][64 * 64];   // [d][key], xor-swizzled key-groups

    const int tid  = threadIdx.x;
    const int lane = tid & 63;
    const int l15  = lane & 15;
    const int quad = lane >> 4;

    const int pair  = blockIdx.y;
    const int split = blockIdx.z;
    const int grp   = pair >> 3;
    const int h     = pair & 7;
    const int q0    = blockIdx.x * 128;
    const int rQ    = grp * SEQL + q0 + (tid >> 6) * 32;
    const int cb    = h * HDIM;
    const int NIT   = (SEQL / 64) / NSPLIT;   // 16
    const int kt0   = split * NIT;

    const _Float16* Kbase = K16 + (size_t)grp * SEQL * DM + cb;
    const _Float16* Vbase = Vt + (size_t)grp * DM * SEQL + (size_t)cb * SEQL;

    // Q fragments (B-operand of S^T): B[n=qrow=l15][k=d=quad*8+j]
    half8v qf[2][2];
#pragma unroll
    for (int qt = 0; qt < 2; ++qt)
#pragma unroll
        for (int ks = 0; ks < 2; ++ks)
            qf[qt][ks] = *(const half8v*)&Q16[(size_t)(rQ + qt * 16 + l15) * DM + cb + ks * 32 + quad * 8];

    floatx4 oacc[2][4], lacc[2];
#pragma unroll
    for (int qt = 0; qt < 2; ++qt) {
        lacc[qt] = (floatx4){0.f, 0.f, 0.f, 0.f};
#pragma unroll
        for (int dt = 0; dt < 4; ++dt) oacc[qt][dt] = (floatx4){0.f, 0.f, 0.f, 0.f};
    }
    half4v ones;
    ones[0] = (_Float16)1.f; ones[1] = (_Float16)1.f; ones[2] = (_Float16)1.f; ones[3] = (_Float16)1.f;

#define STAGE(KT, B)                                                            \
    {                                                                           \
        _Float16* ksb = &Ks[B][0];                                              \
        _Float16* vsb = &Vs[B][0];                                              \
        _Pragma("unroll")                                                       \
        for (int i_ = 0; i_ < 4; ++i_) {                                        \
            const int c_ = i_ * 256 + tid;                                      \
            if (c_ < 512) {                                                     \
                const int key_ = c_ >> 3, g_ = c_ & 7;                          \
                const int dg_ = g_ ^ (key_ & 7);                                \
                gll16(&Kbase[(size_t)((KT) * 64 + key_) * DM + dg_ * 8],        \
                      &ksb[c_ * 8]);                                            \
            } else {                                                            \
                const int cv_ = c_ - 512;                                       \
                const int d_ = cv_ >> 3, g_ = cv_ & 7;                          \
                const int kg_ = g_ ^ (d_ & 7);                                  \
                gll16(&Vbase[(size_t)d_ * SEQL + (KT) * 64 + kg_ * 8],          \
                      &vsb[cv_ * 8]);                                           \
            }                                                                   \
        }                                                                       \
    }

    STAGE(kt0, 0)

    for (int it = 0; it < NIT; ++it) {
        const int cur = it & 1;
        __syncthreads();               // data for it ready; prev readers done
        if (it + 1 < NIT) STAGE(kt0 + it + 1, cur ^ 1)

        const _Float16* ksb = &Ks[cur][0];
        const _Float16* vsb = &Vs[cur][0];

        // S^T = K . Q^T : D[m=key][n=qrow]
        floatx4 st[4][2];
#pragma unroll
        for (int ktile = 0; ktile < 4; ++ktile) {
            const int key = ktile * 16 + l15;
            const half8v kf0 = *(const half8v*)&ksb[key * 64 + ((0 + quad) ^ (key & 7)) * 8];
            const half8v kf1 = *(const half8v*)&ksb[key * 64 + ((4 + quad) ^ (key & 7)) * 8];
#pragma unroll
            for (int qt = 0; qt < 2; ++qt) {
                floatx4 z = {0.f, 0.f, 0.f, 0.f};
                z = __builtin_amdgcn_mfma_f32_16x16x32_f16(kf0, qf[qt][0], z, 0, 0, 0);
                st[ktile][qt] = __builtin_amdgcn_mfma_f32_16x16x32_f16(kf1, qf[qt][1], z, 0, 0, 0);
            }
        }

        // p = 2^s, straight into A-operand regs of 16x16x16 (k=key=quad*4+j)
        half4v pa[4][2];
#pragma unroll
        for (int ktile = 0; ktile < 4; ++ktile)
#pragma unroll
            for (int qt = 0; qt < 2; ++qt)
                pa[ktile][qt] = pack4(__builtin_amdgcn_exp2f(st[ktile][qt][0]),
                                      __builtin_amdgcn_exp2f(st[ktile][qt][1]),
                                      __builtin_amdgcn_exp2f(st[ktile][qt][2]),
                                      __builtin_amdgcn_exp2f(st[ktile][qt][3]));

        // l += P . ones  (same C-layout rows as O)
#pragma unroll
        for (int qt = 0; qt < 2; ++qt)
#pragma unroll
            for (int ktile = 0; ktile < 4; ++ktile)
                lacc[qt] = __builtin_amdgcn_mfma_f32_16x16x16f16(pa[ktile][qt], ones, lacc[qt], 0, 0, 0);

        // O += P . V : B[k=key=quad*4+j][n=d=l15] from Vs[d][key]
#pragma unroll
        for (int dt = 0; dt < 4; ++dt) {
            const int d = dt * 16 + l15;
#pragma unroll
            for (int ktile = 0; ktile < 4; ++ktile) {
                const int G = ktile * 2 + (quad >> 1);
                const int slot = G ^ (d & 7);
                const half4v vf = *(const half4v*)&vsb[d * 64 + slot * 8 + (quad & 1) * 4];
#pragma unroll
                for (int qt = 0; qt < 2; ++qt)
                    oacc[qt][dt] = __builtin_amdgcn_mfma_f32_16x16x16f16(pa[ktile][qt], vf, oacc[qt][dt], 0, 0, 0);
            }
        }
    }

    // epilogue: unnormalized O (f16) + l (f32); rows = qt*16 + quad*4 + r
    _Float16* Op = Opart + (size_t)split * MROWS * DM;
#pragma unroll
    for (int qt = 0; qt < 2; ++qt)
#pragma unroll
        for (int r = 0; r < 4; ++r) {
            const int qrow = rQ + qt * 16 + quad * 4 + r;
            const size_t rowoff = (size_t)qrow * DM + cb;
#pragma unroll
            for (int dt = 0; dt < 4; ++dt)
                Op[rowoff + dt * 16 + l15] = (_Float16)oacc[qt][dt][r];
            if (l15 == 0)
                lpart[((size_t)split * MROWS + qrow) * 8 + h] = lacc[qt][r];
        }
}

// ---------------------------------------------------------------------------
// combine split-K partials: O16 = (O0 + O1) / (l0 + l1)
// thread handles 8 consecutive cols of one row (same head).
// ---------------------------------------------------------------------------
__global__ __launch_bounds__(256) void combine(const _Float16* __restrict__ Opart,
                                               const float* __restrict__ lpart,
                                               _Float16* __restrict__ O16) {
    const size_t idx = (size_t)blockIdx.x * 256 + threadIdx.x;
    const int row = idx >> 6;
    const int c8 = (idx & 63) * 8;
    const int h = c8 >> 6;
    const float l = lpart[(size_t)row * 8 + h] + lpart[((size_t)MROWS + row) * 8 + h];
    const float inv = 1.0f / l;
    const half8v a = *(const half8v*)&Opart[(size_t)row * DM + c8];
    const half8v b = *(const half8v*)&Opart[(size_t)MROWS * DM + (size_t)row * DM + c8];
    half8v o;
#pragma unroll
    for (int i = 0; i < 8; ++i)
        o[i] = (_Float16)(((float)a[i] + (float)b[i]) * inv);
    *(half8v*)&O16[(size_t)row * DM + c8] = o;
}

// ---------------------------------------------------------------------------
extern "C" void kernel_launch(void* const* d_in, const int* in_sizes, int n_in,
                              void* d_out, int out_size, void* d_ws, size_t ws_size,
                              hipStream_t stream) {
    const float* key_in   = (const float*)d_in[0];
    const float* value_in = (const float*)d_in[1];
    const float* query_in = (const float*)d_in[2];
    const float* Wk = (const float*)d_in[3];
    const float* bk = (const float*)d_in[4];
    const float* Wv = (const float*)d_in[5];
    const float* bv = (const float*)d_in[6];
    const float* Wq = (const float*)d_in[7];
    const float* bq = (const float*)d_in[8];
    const float* Wo = (const float*)d_in[9];
    const float* bo = (const float*)d_in[10];
    float* out = (float*)d_out;

    const size_t MAT = (size_t)MROWS * DM;   // 4M elems
    _Float16* Xq16 = (_Float16*)d_ws;        // 8 MB (reused as Opart[0])
    _Float16* Xk16 = Xq16 + MAT;             // 8 MB (reused as Opart[1])
    _Float16* Xv16 = Xk16 + MAT;             // 8 MB (reused as O16)
    _Float16* Q16  = Xv16 + MAT;
    _Float16* K16  = Q16 + MAT;
    _Float16* Vtb  = K16 + MAT;              // transposed V, written by V-GEMM
    _Float16* Wqt  = Vtb + MAT;
    _Float16* Wkt  = Wqt + DM * DM;
    _Float16* Wvt  = Wkt + DM * DM;
    _Float16* Wot  = Wvt + DM * DM;
    float*    lpart = (float*)(Wot + DM * DM);  // 2*MROWS*8 f32 = 512 KB
    _Float16* Opart = Xq16;                  // aliases Xq16+Xk16 (dead after proj)
    _Float16* O16   = Xv16;                  // alias: Xv16 dead after proj

    const dim3 blk(256);

    cast3<<<dim3(2048, 1, 3), blk, 0, stream>>>(query_in, key_in, value_in, Xq16, Xk16, Xv16);
    transw<<<dim3(16, 16, 4), blk, 0, stream>>>(Wq, Wk, Wv, Wo, Wqt, Wkt, Wvt, Wot);

    // Q/K/V projections in one dispatch; V writes Vt layout (mode 1)
    gemm_f16<<<dim3(DM / 64, MROWS / 128, 3), blk, 0, stream>>>(
        Xq16, Xk16, Xv16, Wqt, Wkt, Wvt, bq, bk, bv,
        (void*)Q16, (void*)K16, (void*)Vtb, 0 | (0 << 4) | (1 << 8), CEXP);

    attn_mfma<<<dim3(SEQL / 128, 32, NSPLIT), blk, 0, stream>>>(Q16, K16, Vtb, Opart, lpart);
    combine<<<dim3(MROWS * DM / 8 / 256), blk, 0, stream>>>(Opart, lpart, O16);

    gemm_f16<<<dim3(DM / 64, MROWS / 128, 1), blk, 0, stream>>>(
        O16, O16, O16, Wot, Wot, Wot, bo, bo, bo,
        (void*)out, (void*)out, (void*)out, 2, 1.0f);
}

// Round 7
// 201.605 us; speedup vs baseline: 1.0596x; 1.0596x over previous
//
#include <hip/hip_runtime.h>
#include <math.h>

#define MROWS 8192   // T*B flat rows
#define DM    512    // d_model
#define SEQL  2048   // attention sequence (rows per batch group)
#define HDIM  64
#define NSPLIT 2     // key-dimension split for attention occupancy

typedef __attribute__((ext_vector_type(4))) float floatx4;
typedef _Float16 half2v __attribute__((ext_vector_type(2)));
typedef _Float16 half4v __attribute__((ext_vector_type(4)));
typedef _Float16 half8v __attribute__((ext_vector_type(8)));

#define CEXP 0.18033688011f   // log2(e)/8 — folded into Wq/bq at prep time

// async global->LDS, 16B per lane; LDS dst must be uniform_base + lane*16
__device__ __forceinline__ void gll16(const void* g, void* l) {
    __builtin_amdgcn_global_load_lds(
        (const __attribute__((address_space(1))) unsigned int*)g,
        (__attribute__((address_space(3))) unsigned int*)l, 16, 0, 0);
}

__device__ __forceinline__ half4v pack4(float a, float b, float c, float d) {
    half2v lo = __builtin_bit_cast(half2v, __builtin_amdgcn_cvt_pkrtz(a, b));
    half2v hi = __builtin_bit_cast(half2v, __builtin_amdgcn_cvt_pkrtz(c, d));
    half4v r;
    r[0] = lo[0]; r[1] = lo[1]; r[2] = hi[0]; r[3] = hi[1];
    return r;
}

// ---------------------------------------------------------------------------
// transpose+cast 512x512 f32 weights -> f16 [N][K]; Wq (z==0) pre-scaled by CEXP
// ---------------------------------------------------------------------------
__global__ __launch_bounds__(256) void transw(const float* __restrict__ w0,
                                              const float* __restrict__ w1,
                                              const float* __restrict__ w2,
                                              const float* __restrict__ w3,
                                              _Float16* __restrict__ t0,
                                              _Float16* __restrict__ t1,
                                              _Float16* __restrict__ t2,
                                              _Float16* __restrict__ t3) {
    __shared__ float tile[32][33];
    const float* W = blockIdx.z == 0 ? w0 : (blockIdx.z == 1 ? w1 : (blockIdx.z == 2 ? w2 : w3));
    _Float16* T = blockIdx.z == 0 ? t0 : (blockIdx.z == 1 ? t1 : (blockIdx.z == 2 ? t2 : t3));
    const float sc = (blockIdx.z == 0) ? CEXP : 1.0f;
    const int tx = threadIdx.x & 31, ty = threadIdx.x >> 5;  // 32 x 8
    const int x = blockIdx.x * 32 + tx;
    const int y0 = blockIdx.y * 32;
#pragma unroll
    for (int i = 0; i < 4; ++i)
        tile[ty + i * 8][tx] = W[(size_t)(y0 + ty + i * 8) * DM + x];
    __syncthreads();
    const int xo = y0 + tx;
#pragma unroll
    for (int i = 0; i < 4; ++i)
        T[(size_t)(blockIdx.x * 32 + ty + i * 8) * DM + xo] = (_Float16)(tile[tx][ty + i * 8] * sc);
}

// ---------------------------------------------------------------------------
// Projection GEMM, M-narrow/N-wide: block = 32 M-rows x FULL N=512, BK=32.
// A (f32 input) is read ONCE and cast f32->f16 during staging (no cast3).
// B (weights, 0.5 MB) re-read per M-block but L2-resident -> cheap.
// grid (MROWS/32=256, 3 matrices).  4 waves x 128 N-cols, acc[2][8].
// z==2 (V) writes the transposed Vt layout directly.
// ---------------------------------------------------------------------------
__global__ __launch_bounds__(256, 3) void proj_gemm(
        const float* __restrict__ q32, const float* __restrict__ k32, const float* __restrict__ v32,
        const _Float16* __restrict__ Wq, const _Float16* __restrict__ Wk, const _Float16* __restrict__ Wv,
        const float* __restrict__ bq, const float* __restrict__ bk, const float* __restrict__ bv,
        _Float16* __restrict__ Qo, _Float16* __restrict__ Ko, _Float16* __restrict__ Vto) {
    __shared__ _Float16 Bs[512 * 32];   // 32 KB  [n][k-slice], xor-swizzled
    __shared__ _Float16 As[32 * 32];    //  2 KB  [m][k-slice], xor-swizzled
    const int z = blockIdx.y;
    const float* A32    = z == 0 ? q32 : (z == 1 ? k32 : v32);
    const _Float16* Bt  = z == 0 ? Wq : (z == 1 ? Wk : Wv);
    const float* bias   = z == 0 ? bq : (z == 1 ? bk : bv);
    const float bscale  = z == 0 ? CEXP : 1.0f;

    const int tid = threadIdx.x;
    const int w = tid >> 6;
    const int l15 = tid & 15, quad = (tid & 63) >> 4;
    const int m0 = blockIdx.x * 32;

    floatx4 acc[2][8];
#pragma unroll
    for (int i = 0; i < 2; ++i)
#pragma unroll
        for (int j = 0; j < 8; ++j) acc[i][j] = (floatx4){0.f, 0.f, 0.f, 0.f};

    for (int kt = 0; kt < DM / 32; ++kt) {   // 16 iters
        __syncthreads();
        // B: 512 rows x 32 k = 2048 chunks of 8 f16 -> 8 gll16/thread
#pragma unroll
        for (int i = 0; i < 8; ++i) {
            const int c = i * 256 + tid;
            const int row = c >> 2, g = c & 3;
            const int kg = g ^ (row & 3);
            gll16(&Bt[(size_t)row * DM + kt * 32 + kg * 8], &Bs[c * 8]);
        }
        // A: 32 rows x 32 k = 128 chunks; threads 0..127, f32->f16 cast fused
        if (tid < 128) {
            const int c = tid;
            const int row = c >> 2, g = c & 3;
            const int kg = g ^ (row & 3);
            const float* src = &A32[(size_t)(m0 + row) * DM + kt * 32 + kg * 8];
            const float4 f0 = *(const float4*)&src[0];
            const float4 f1 = *(const float4*)&src[4];
            half8v o;
            o[0] = (_Float16)f0.x; o[1] = (_Float16)f0.y; o[2] = (_Float16)f0.z; o[3] = (_Float16)f0.w;
            o[4] = (_Float16)f1.x; o[5] = (_Float16)f1.y; o[6] = (_Float16)f1.z; o[7] = (_Float16)f1.w;
            *(half8v*)&As[c * 8] = o;
        }
        __syncthreads();
        half8v af[2], bfr[8];
#pragma unroll
        for (int i = 0; i < 2; ++i) {
            const int row = i * 16 + l15;
            af[i] = *(const half8v*)&As[row * 32 + (quad ^ (row & 3)) * 8];
        }
#pragma unroll
        for (int j = 0; j < 8; ++j) {
            const int row = w * 128 + j * 16 + l15;
            bfr[j] = *(const half8v*)&Bs[row * 32 + (quad ^ (row & 3)) * 8];
        }
#pragma unroll
        for (int i = 0; i < 2; ++i)
#pragma unroll
            for (int j = 0; j < 8; ++j)
                acc[i][j] = __builtin_amdgcn_mfma_f32_16x16x32_f16(af[i], bfr[j], acc[i][j], 0, 0, 0);
    }
    // epilogue
#pragma unroll
    for (int j = 0; j < 8; ++j) {
        const int col = w * 128 + j * 16 + l15;
        const float bv4 = bias[col] * bscale;
#pragma unroll
        for (int i = 0; i < 2; ++i) {
            const int rb = m0 + i * 16 + quad * 4;
            if (z == 2) {   // Vt[g][col][seq]: 4 consecutive seq -> one 8B store
                const int g = rb >> 11, seq = rb & 2047;
                half4v pv;
#pragma unroll
                for (int r = 0; r < 4; ++r) pv[r] = (_Float16)(acc[i][j][r] + bv4);
                *(half4v*)&Vto[((size_t)g * DM + col) * SEQL + seq] = pv;
            } else {
                _Float16* oh = z == 0 ? Qo : Ko;
#pragma unroll
                for (int r = 0; r < 4; ++r)
                    oh[(size_t)(rb + r) * DM + col] = (_Float16)(acc[i][j][r] + bv4);
            }
        }
    }
}

// ---------------------------------------------------------------------------
// Output GEMM with fused split-K combine: A = (Opart0 + Opart1) / (l0+l1),
// computed in f32 during A-staging.  Head of GEMM k-tile kt is exactly kt
// (64-col k-tiles align with heads).  block = 32 M x 256 N, BK=64,
// grid (2, 256).  4 waves x 64 N-cols, acc[2][4].  f32 output + bias.
// ---------------------------------------------------------------------------
__global__ __launch_bounds__(256, 4) void out_gemm(
        const _Float16* __restrict__ Op0, const _Float16* __restrict__ Op1,
        const float* __restrict__ lp,
        const _Float16* __restrict__ Wo, const float* __restrict__ bo,
        float* __restrict__ out) {
    __shared__ _Float16 Bs[256 * 64];   // 32 KB
    __shared__ _Float16 As[32 * 64];    //  4 KB
    const int tid = threadIdx.x;
    const int w = tid >> 6;
    const int l15 = tid & 15, quad = (tid & 63) >> 4;
    const int n0 = blockIdx.x * 256, m0 = blockIdx.y * 32;

    floatx4 acc[2][4];
#pragma unroll
    for (int i = 0; i < 2; ++i)
#pragma unroll
        for (int j = 0; j < 4; ++j) acc[i][j] = (floatx4){0.f, 0.f, 0.f, 0.f};

    for (int kt = 0; kt < DM / 64; ++kt) {   // 8 iters; head = kt
        __syncthreads();
        // B: 256 rows x 64 k = 2048 chunks -> 8 gll16/thread
#pragma unroll
        for (int i = 0; i < 8; ++i) {
            const int c = i * 256 + tid;
            const int row = c >> 3, g = c & 7;
            const int kg = g ^ (row & 7);
            gll16(&Wo[(size_t)(n0 + row) * DM + kt * 64 + kg * 8], &Bs[c * 8]);
        }
        // A: 32 rows x 64 k = 256 chunks; fused combine in f32
        {
            const int c = tid;
            const int row = c >> 3, g = c & 7;
            const int kg = g ^ (row & 7);
            const int grow = m0 + row;
            const size_t off = (size_t)grow * DM + kt * 64 + kg * 8;
            const half8v a = *(const half8v*)&Op0[off];
            const half8v b = *(const half8v*)&Op1[off];
            const float inv = 1.0f / (lp[(size_t)grow * 8 + kt] +
                                      lp[((size_t)MROWS + grow) * 8 + kt]);
            half8v s;
#pragma unroll
            for (int e = 0; e < 8; ++e)
                s[e] = (_Float16)(((float)a[e] + (float)b[e]) * inv);
            *(half8v*)&As[c * 8] = s;
        }
        __syncthreads();
#pragma unroll
        for (int ks = 0; ks < 2; ++ks) {
            half8v af[2], bfr[4];
#pragma unroll
            for (int i = 0; i < 2; ++i) {
                const int row = i * 16 + l15;
                af[i] = *(const half8v*)&As[row * 64 + ((ks * 4 + quad) ^ (row & 7)) * 8];
            }
#pragma unroll
            for (int j = 0; j < 4; ++j) {
                const int row = w * 64 + j * 16 + l15;
                bfr[j] = *(const half8v*)&Bs[row * 64 + ((ks * 4 + quad) ^ (row & 7)) * 8];
            }
#pragma unroll
            for (int i = 0; i < 2; ++i)
#pragma unroll
                for (int j = 0; j < 4; ++j)
                    acc[i][j] = __builtin_amdgcn_mfma_f32_16x16x32_f16(af[i], bfr[j], acc[i][j], 0, 0, 0);
        }
    }
#pragma unroll
    for (int j = 0; j < 4; ++j) {
        const int col = n0 + w * 64 + j * 16 + l15;
        const float bv4 = bo[col];
#pragma unroll
        for (int i = 0; i < 2; ++i) {
            const int rb = m0 + i * 16 + quad * 4;
#pragma unroll
            for (int r = 0; r < 4; ++r)
                out[(size_t)(rb + r) * DM + col] = acc[i][j][r] + bv4;
        }
    }
}

// ---------------------------------------------------------------------------
// Flash attention, f16 MFMA, S^T orientation, fixed-scale softmax, split-K.
// grid (16 q-tiles, 32 (g,h) pairs, NSPLIT key-splits); 256 threads.
// Each split covers SEQL/NSPLIT keys; writes unnormalized O (f16) + l (f32).
// ---------------------------------------------------------------------------
__global__ __launch_bounds__(256, 4) void attn_mfma(const _Float16* __restrict__ Q16,
                                                    const _Float16* __restrict__ K16,
                                                    const _Float16* __restrict__ Vt,
                                                    _Float16* __restrict__ Opart,
                                                    float* __restrict__ lpart) {
    __shared__ _Float16 Ks[2][64 * 64];   // [key][d], xor-swizzled d-groups
    __shared__ _Float16 Vs[2][64 * 64];   // [d][key], xor-swizzled key-groups

    const int tid  = threadIdx.x;
    const int lane = tid & 63;
    const int l15  = lane & 15;
    const int quad = lane >> 4;

    const int pair  = blockIdx.y;
    const int split = blockIdx.z;
    const int grp   = pair >> 3;
    const int h     = pair & 7;
    const int q0    = blockIdx.x * 128;
    const int rQ    = grp * SEQL + q0 + (tid >> 6) * 32;
    const int cb    = h * HDIM;
    const int NIT   = (SEQL / 64) / NSPLIT;   // 16
    const int kt0   = split * NIT;

    const _Float16* Kbase = K16 + (size_t)grp * SEQL * DM + cb;
    const _Float16* Vbase = Vt + (size_t)grp * DM * SEQL + (size_t)cb * SEQL;

    // Q fragments (B-operand of S^T): B[n=qrow=l15][k=d=quad*8+j]
    half8v qf[2][2];
#pragma unroll
    for (int qt = 0; qt < 2; ++qt)
#pragma unroll
        for (int ks = 0; ks < 2; ++ks)
            qf[qt][ks] = *(const half8v*)&Q16[(size_t)(rQ + qt * 16 + l15) * DM + cb + ks * 32 + quad * 8];

    floatx4 oacc[2][4], lacc[2];
#pragma unroll
    for (int qt = 0; qt < 2; ++qt) {
        lacc[qt] = (floatx4){0.f, 0.f, 0.f, 0.f};
#pragma unroll
        for (int dt = 0; dt < 4; ++dt) oacc[qt][dt] = (floatx4){0.f, 0.f, 0.f, 0.f};
    }
    half4v ones;
    ones[0] = (_Float16)1.f; ones[1] = (_Float16)1.f; ones[2] = (_Float16)1.f; ones[3] = (_Float16)1.f;

#define STAGE(KT, B)                                                            \
    {                                                                           \
        _Float16* ksb = &Ks[B][0];                                              \
        _Float16* vsb = &Vs[B][0];                                              \
        _Pragma("unroll")                                                       \
        for (int i_ = 0; i_ < 4; ++i_) {                                        \
            const int c_ = i_ * 256 + tid;                                      \
            if (c_ < 512) {                                                     \
                const int key_ = c_ >> 3, g_ = c_ & 7;                          \
                const int dg_ = g_ ^ (key_ & 7);                                \
                gll16(&Kbase[(size_t)((KT) * 64 + key_) * DM + dg_ * 8],        \
                      &ksb[c_ * 8]);                                            \
            } else {                                                            \
                const int cv_ = c_ - 512;                                       \
                const int d_ = cv_ >> 3, g_ = cv_ & 7;                          \
                const int kg_ = g_ ^ (d_ & 7);                                  \
                gll16(&Vbase[(size_t)d_ * SEQL + (KT) * 64 + kg_ * 8],          \
                      &vsb[cv_ * 8]);                                           \
            }                                                                   \
        }                                                                       \
    }

    STAGE(kt0, 0)

    for (int it = 0; it < NIT; ++it) {
        const int cur = it & 1;
        __syncthreads();               // data for it ready; prev readers done
        if (it + 1 < NIT) STAGE(kt0 + it + 1, cur ^ 1)

        const _Float16* ksb = &Ks[cur][0];
        const _Float16* vsb = &Vs[cur][0];

        // S^T = K . Q^T : D[m=key][n=qrow]
        floatx4 st[4][2];
#pragma unroll
        for (int ktile = 0; ktile < 4; ++ktile) {
            const int key = ktile * 16 + l15;
            const half8v kf0 = *(const half8v*)&ksb[key * 64 + ((0 + quad) ^ (key & 7)) * 8];
            const half8v kf1 = *(const half8v*)&ksb[key * 64 + ((4 + quad) ^ (key & 7)) * 8];
#pragma unroll
            for (int qt = 0; qt < 2; ++qt) {
                floatx4 z = {0.f, 0.f, 0.f, 0.f};
                z = __builtin_amdgcn_mfma_f32_16x16x32_f16(kf0, qf[qt][0], z, 0, 0, 0);
                st[ktile][qt] = __builtin_amdgcn_mfma_f32_16x16x32_f16(kf1, qf[qt][1], z, 0, 0, 0);
            }
        }

        // p = 2^s, straight into A-operand regs of 16x16x16 (k=key=quad*4+j)
        half4v pa[4][2];
#pragma unroll
        for (int ktile = 0; ktile < 4; ++ktile)
#pragma unroll
            for (int qt = 0; qt < 2; ++qt)
                pa[ktile][qt] = pack4(__builtin_amdgcn_exp2f(st[ktile][qt][0]),
                                      __builtin_amdgcn_exp2f(st[ktile][qt][1]),
                                      __builtin_amdgcn_exp2f(st[ktile][qt][2]),
                                      __builtin_amdgcn_exp2f(st[ktile][qt][3]));

        // l += P . ones  (same C-layout rows as O)
#pragma unroll
        for (int qt = 0; qt < 2; ++qt)
#pragma unroll
            for (int ktile = 0; ktile < 4; ++ktile)
                lacc[qt] = __builtin_amdgcn_mfma_f32_16x16x16f16(pa[ktile][qt], ones, lacc[qt], 0, 0, 0);

        // O += P . V : B[k=key=quad*4+j][n=d=l15] from Vs[d][key]
#pragma unroll
        for (int dt = 0; dt < 4; ++dt) {
            const int d = dt * 16 + l15;
#pragma unroll
            for (int ktile = 0; ktile < 4; ++ktile) {
                const int G = ktile * 2 + (quad >> 1);
                const int slot = G ^ (d & 7);
                const half4v vf = *(const half4v*)&vsb[d * 64 + slot * 8 + (quad & 1) * 4];
#pragma unroll
                for (int qt = 0; qt < 2; ++qt)
                    oacc[qt][dt] = __builtin_amdgcn_mfma_f32_16x16x16f16(pa[ktile][qt], vf, oacc[qt][dt], 0, 0, 0);
            }
        }
    }

    // epilogue: unnormalized O (f16) + l (f32); rows = qt*16 + quad*4 + r
    _Float16* Op = Opart + (size_t)split * MROWS * DM;
#pragma unroll
    for (int qt = 0; qt < 2; ++qt)
#pragma unroll
        for (int r = 0; r < 4; ++r) {
            const int qrow = rQ + qt * 16 + quad * 4 + r;
            const size_t rowoff = (size_t)qrow * DM + cb;
#pragma unroll
            for (int dt = 0; dt < 4; ++dt)
                Op[rowoff + dt * 16 + l15] = (_Float16)oacc[qt][dt][r];
            if (l15 == 0)
                lpart[((size_t)split * MROWS + qrow) * 8 + h] = lacc[qt][r];
        }
}

// ---------------------------------------------------------------------------
extern "C" void kernel_launch(void* const* d_in, const int* in_sizes, int n_in,
                              void* d_out, int out_size, void* d_ws, size_t ws_size,
                              hipStream_t stream) {
    const float* key_in   = (const float*)d_in[0];
    const float* value_in = (const float*)d_in[1];
    const float* query_in = (const float*)d_in[2];
    const float* Wk = (const float*)d_in[3];
    const float* bk = (const float*)d_in[4];
    const float* Wv = (const float*)d_in[5];
    const float* bv = (const float*)d_in[6];
    const float* Wq = (const float*)d_in[7];
    const float* bq = (const float*)d_in[8];
    const float* Wo = (const float*)d_in[9];
    const float* bo = (const float*)d_in[10];
    float* out = (float*)d_out;

    const size_t MAT = (size_t)MROWS * DM;   // 4M elems
    _Float16* Q16  = (_Float16*)d_ws;        // 8 MB
    _Float16* K16  = Q16 + MAT;              // 8 MB
    _Float16* Vtb  = K16 + MAT;              // 8 MB (transposed V, written by proj z=2)
    _Float16* Wqt  = Vtb + MAT;              // 0.5 MB each
    _Float16* Wkt  = Wqt + DM * DM;
    _Float16* Wvt  = Wkt + DM * DM;
    _Float16* Wot  = Wvt + DM * DM;
    float*    lpart = (float*)(Wot + DM * DM);       // 0.5 MB
    _Float16* Opart = (_Float16*)(lpart + 2 * MROWS * 8);  // 16 MB -> total 42.5 MB

    const dim3 blk(256);

    transw<<<dim3(16, 16, 4), blk, 0, stream>>>(Wq, Wk, Wv, Wo, Wqt, Wkt, Wvt, Wot);

    // fused cast + Q/K/V projections; V writes Vt layout directly
    proj_gemm<<<dim3(MROWS / 32, 3), blk, 0, stream>>>(
        query_in, key_in, value_in, Wqt, Wkt, Wvt, bq, bk, bv, Q16, K16, Vtb);

    attn_mfma<<<dim3(SEQL / 128, 32, NSPLIT), blk, 0, stream>>>(Q16, K16, Vtb, Opart, lpart);

    // fused combine + output GEMM
    out_gemm<<<dim3(2, MROWS / 32), blk, 0, stream>>>(
        Opart, Opart + MAT, lpart, Wot, bo, out);
}